// Round 1
// baseline (804.811 us; speedup 1.0000x reference)
//
#include <hip/hip_runtime.h>
#include <stdint.h>

#define NROWS 32768
#define DDIM  512
#define KDIM  512

__device__ __forceinline__ float b2f(unsigned short u) {
  return __uint_as_float(((unsigned int)u) << 16);
}
__device__ __forceinline__ unsigned short f2bf(float f) {
  unsigned int u = __float_as_uint(f);
  u += 0x7FFFu + ((u >> 16) & 1u);   // round-to-nearest-even
  return (unsigned short)(u >> 16);
}

typedef __attribute__((ext_vector_type(8))) short bf16x8;
typedef __attribute__((ext_vector_type(4))) float f32x4;

// ---------------------------------------------------------------------------
// prep: row inverse-norms for z1/z2 (rows 0..65535) and normalized bf16 weight
// ---------------------------------------------------------------------------
__global__ __launch_bounds__(256) void prep_kernel(
    const float* __restrict__ z1, const float* __restrict__ z2,
    const float* __restrict__ w, float* __restrict__ rnorm,
    unsigned short* __restrict__ wnb) {
  const int tid = threadIdx.x;
  const int wv = tid >> 6, ln = tid & 63;
  const int row = blockIdx.x * 4 + wv;   // 0..66047
  const float* src;
  if (row < NROWS)        src = z1 + (size_t)row * DDIM;
  else if (row < 2*NROWS) src = z2 + (size_t)(row - NROWS) * DDIM;
  else                    src = w  + (size_t)(row - 2*NROWS) * DDIM;
  float4 v0 = ((const float4*)src)[ln*2];
  float4 v1 = ((const float4*)src)[ln*2+1];
  float ss = v0.x*v0.x + v0.y*v0.y + v0.z*v0.z + v0.w*v0.w
           + v1.x*v1.x + v1.y*v1.y + v1.z*v1.z + v1.w*v1.w;
  #pragma unroll
  for (int off = 1; off < 64; off <<= 1) ss += __shfl_xor(ss, off);
  float rn = 1.0f / fmaxf(sqrtf(ss), 1e-12f);
  if (row < 2*NROWS) {
    if (ln == 0) rnorm[row] = rn;
  } else {
    int r = row - 2*NROWS;
    ushort4 o0 = make_ushort4(f2bf(v0.x*rn), f2bf(v0.y*rn), f2bf(v0.z*rn), f2bf(v0.w*rn));
    ushort4 o1 = make_ushort4(f2bf(v1.x*rn), f2bf(v1.y*rn), f2bf(v1.z*rn), f2bf(v1.w*rn));
    ushort4* dst = (ushort4*)(wnb + (size_t)r*DDIM + ln*8);
    dst[0] = o0; dst[1] = o1;
  }
}

// ---------------------------------------------------------------------------
// initvecs: zero the 20 column-sum buffers (T[20][2*512]) and the output
// ---------------------------------------------------------------------------
__global__ void initvecs_kernel(float* __restrict__ T, float* __restrict__ out) {
  int i = blockIdx.x * 256 + threadIdx.x;
  if (i < 20 * 1024) T[i] = 0.f;
  if (i == 0) out[0] = 0.f;
}

// ---------------------------------------------------------------------------
// gemm: zc[r,c] = sum_d (z[r,d]*rnorm[r]) * wnb[c,d]   (bf16 MFMA, A*B^T)
// 128x128 tile, BK=32, 4 waves each 64x64 via 4x4 of 16x16x32 MFMAs
// ---------------------------------------------------------------------------
__global__ __launch_bounds__(256) void gemm_kernel(
    const float* __restrict__ z1, const float* __restrict__ z2,
    const float* __restrict__ rnorm, const unsigned short* __restrict__ wnb,
    unsigned short* __restrict__ zc) {
  constexpr int LDT = 40;   // padded LDS stride (elements): 80B rows, 16B aligned
  __shared__ unsigned short As[128 * LDT];
  __shared__ unsigned short Bs[128 * LDT];
  const int tid = threadIdx.x;
  const int colBase = blockIdx.x * 128;
  const int rowBase = blockIdx.y * 128;
  const float* Aptr = (rowBase < NROWS) ? (z1 + (size_t)rowBase * DDIM)
                                        : (z2 + (size_t)(rowBase - NROWS) * DDIM);
  const int wv = tid >> 6, ln = tid & 63;
  const int wm = wv & 1, wn = wv >> 1;
  const int lrow = ln & 15, quad = ln >> 4;

  f32x4 acc[4][4] = {};

  for (int k0 = 0; k0 < DDIM; k0 += 32) {
    // stage A (fp32 -> normalized bf16): 128 rows x 32 k
    #pragma unroll
    for (int i = 0; i < 4; i++) {
      int idx = i * 256 + tid;            // 0..1023
      int r = idx >> 3;                   // 0..127
      int kk = (idx & 7) * 4;             // 0..28
      float4 v = *(const float4*)(Aptr + (size_t)r * DDIM + k0 + kk);
      float rn = rnorm[rowBase + r];
      ushort4 o = make_ushort4(f2bf(v.x*rn), f2bf(v.y*rn), f2bf(v.z*rn), f2bf(v.w*rn));
      *(ushort4*)(&As[r * LDT + kk]) = o;
    }
    // stage B (bf16 weight): 128 rows x 32 k
    #pragma unroll
    for (int i = 0; i < 2; i++) {
      int idx = i * 256 + tid;            // 0..511
      int r = idx >> 2;                   // 0..127
      int kk = (idx & 3) * 8;             // 0..24
      float4 v = *(const float4*)(wnb + (size_t)(colBase + r) * DDIM + k0 + kk);
      *(float4*)(&Bs[r * LDT + kk]) = v;
    }
    __syncthreads();
    bf16x8 af[4], bfr[4];
    #pragma unroll
    for (int mi = 0; mi < 4; mi++)
      af[mi] = *(const bf16x8*)(&As[(64*wm + 16*mi + lrow) * LDT + quad*8]);
    #pragma unroll
    for (int ni = 0; ni < 4; ni++)
      bfr[ni] = *(const bf16x8*)(&Bs[(64*wn + 16*ni + lrow) * LDT + quad*8]);
    #pragma unroll
    for (int mi = 0; mi < 4; mi++)
      #pragma unroll
      for (int ni = 0; ni < 4; ni++)
        acc[mi][ni] = __builtin_amdgcn_mfma_f32_16x16x32_bf16(
            af[mi], bfr[ni], acc[mi][ni], 0, 0, 0);
    __syncthreads();
  }
  // epilogue: C/D layout col=lane&15, row=(lane>>4)*4+reg
  #pragma unroll
  for (int mi = 0; mi < 4; mi++)
    #pragma unroll
    for (int ni = 0; ni < 4; ni++)
      #pragma unroll
      for (int r = 0; r < 4; r++) {
        size_t grow = (size_t)rowBase + 64*wm + 16*mi + quad*4 + r;
        int gcol = colBase + 64*wn + 16*ni + lrow;
        zc[grow * KDIM + gcol] = f2bf(acc[mi][ni][r]);
      }
}

// ---------------------------------------------------------------------------
// sinkhorn fused pass over both matrices:
//   mode 0: T0[k] = sum_rows exp(zc/eps)              (b == 1)
//   mode 1: a_k = 1/(K*Tprev[k]); per row s = sum_k M*a; b = 1/(B*s);
//           Tnext[k] += sum_rows M[k]*b
// rows 0..32767 -> matrix 0 (zc1), 32768..65535 -> matrix 1 (zc2)
// ---------------------------------------------------------------------------
__global__ __launch_bounds__(256) void pass_kernel(
    const unsigned short* __restrict__ zc,
    const float* __restrict__ Tprev, float* __restrict__ Tnext, int mode) {
  __shared__ float red[4 * 512];
  const int tid = threadIdx.x;
  const int wv = tid >> 6, ln = tid & 63;
  const int gw = blockIdx.x * 4 + wv;       // 0..2047
  const size_t row0 = (size_t)gw * 32;
  const int mat = gw >> 10;                 // 0 or 1
  float a[8];
  if (mode) {
    #pragma unroll
    for (int j = 0; j < 8; j++) a[j] = 1.0f / (512.0f * Tprev[mat*512 + ln*8 + j]);
  }
  float acc[8] = {0,0,0,0,0,0,0,0};
  const unsigned short* base = zc + row0 * 512 + ln * 8;
  for (int r = 0; r < 32; r++) {
    const ushort4* p = (const ushort4*)(base + (size_t)r * 512);
    ushort4 u0 = p[0], u1 = p[1];
    float e[8];
    e[0]=__expf(b2f(u0.x)*20.f); e[1]=__expf(b2f(u0.y)*20.f);
    e[2]=__expf(b2f(u0.z)*20.f); e[3]=__expf(b2f(u0.w)*20.f);
    e[4]=__expf(b2f(u1.x)*20.f); e[5]=__expf(b2f(u1.y)*20.f);
    e[6]=__expf(b2f(u1.z)*20.f); e[7]=__expf(b2f(u1.w)*20.f);
    if (mode) {
      float part = e[0]*a[0]+e[1]*a[1]+e[2]*a[2]+e[3]*a[3]
                 + e[4]*a[4]+e[5]*a[5]+e[6]*a[6]+e[7]*a[7];
      #pragma unroll
      for (int off = 1; off < 64; off <<= 1) part += __shfl_xor(part, off);
      float b = 1.0f / (32768.0f * part);
      #pragma unroll
      for (int j = 0; j < 8; j++) acc[j] += e[j] * b;
    } else {
      #pragma unroll
      for (int j = 0; j < 8; j++) acc[j] += e[j];
    }
  }
  #pragma unroll
  for (int j = 0; j < 8; j++) red[wv*512 + ln*8 + j] = acc[j];
  __syncthreads();
  const int bmat = blockIdx.x >> 8;         // all 4 waves of a block share matrix
  #pragma unroll
  for (int t = 0; t < 2; t++) {
    int k = tid + t * 256;
    float s = red[k] + red[512 + k] + red[1024 + k] + red[1536 + k];
    unsafeAtomicAdd(&Tnext[bmat*512 + k], s);
  }
}

// ---------------------------------------------------------------------------
// loss: a20 = 1/(K*T19); per row: q = M*a/s (s = sum_k M*a);
// logp = z/tau - logsumexp(z/tau);  out -= (sum_k q1*logp2 + q2*logp1)/N
// ---------------------------------------------------------------------------
__global__ __launch_bounds__(256) void loss_kernel(
    const unsigned short* __restrict__ zc,
    const float* __restrict__ T19, float* __restrict__ out) {
  const int tid = threadIdx.x;
  const int wv = tid >> 6, ln = tid & 63;
  const int gw = blockIdx.x * 4 + wv;       // 0..2047
  const size_t row0 = (size_t)gw * 16;
  float a1[8], a2[8];
  #pragma unroll
  for (int j = 0; j < 8; j++) {
    a1[j] = 1.0f / (512.0f * T19[ln*8 + j]);
    a2[j] = 1.0f / (512.0f * T19[512 + ln*8 + j]);
  }
  const float invTau = 1.0f / 0.3f;
  float part = 0.f;
  for (int r = 0; r < 16; r++) {
    size_t b = row0 + r;
    const ushort4* p1 = (const ushort4*)(zc + b * 512 + ln * 8);
    const ushort4* p2 = (const ushort4*)(zc + (b + NROWS) * 512 + ln * 8);
    ushort4 u10 = p1[0], u11 = p1[1], u20 = p2[0], u21 = p2[1];
    float zf1[8], zf2[8];
    zf1[0]=b2f(u10.x); zf1[1]=b2f(u10.y); zf1[2]=b2f(u10.z); zf1[3]=b2f(u10.w);
    zf1[4]=b2f(u11.x); zf1[5]=b2f(u11.y); zf1[6]=b2f(u11.z); zf1[7]=b2f(u11.w);
    zf2[0]=b2f(u20.x); zf2[1]=b2f(u20.y); zf2[2]=b2f(u20.z); zf2[3]=b2f(u20.w);
    zf2[4]=b2f(u21.x); zf2[5]=b2f(u21.y); zf2[6]=b2f(u21.z); zf2[7]=b2f(u21.w);
    float m1 = -1e30f, m2 = -1e30f;
    #pragma unroll
    for (int j = 0; j < 8; j++) { m1 = fmaxf(m1, zf1[j]); m2 = fmaxf(m2, zf2[j]); }
    #pragma unroll
    for (int off = 1; off < 64; off <<= 1) {
      m1 = fmaxf(m1, __shfl_xor(m1, off));
      m2 = fmaxf(m2, __shfl_xor(m2, off));
    }
    float se1 = 0.f, se2 = 0.f;
    #pragma unroll
    for (int j = 0; j < 8; j++) {
      se1 += __expf((zf1[j] - m1) * invTau);
      se2 += __expf((zf2[j] - m2) * invTau);
    }
    #pragma unroll
    for (int off = 1; off < 64; off <<= 1) {
      se1 += __shfl_xor(se1, off);
      se2 += __shfl_xor(se2, off);
    }
    float ls1 = m1 * invTau + __logf(se1);
    float ls2 = m2 * invTau + __logf(se2);
    float s1 = 0.f, n1 = 0.f, s2 = 0.f, n2 = 0.f;
    #pragma unroll
    for (int j = 0; j < 8; j++) {
      float e1 = __expf(zf1[j] * 20.f) * a1[j];
      s1 += e1; n1 += e1 * (zf2[j] * invTau - ls2);
      float e2 = __expf(zf2[j] * 20.f) * a2[j];
      s2 += e2; n2 += e2 * (zf1[j] * invTau - ls1);
    }
    #pragma unroll
    for (int off = 1; off < 64; off <<= 1) {
      s1 += __shfl_xor(s1, off); n1 += __shfl_xor(n1, off);
      s2 += __shfl_xor(s2, off); n2 += __shfl_xor(n2, off);
    }
    part += n1 / s1 + n2 / s2;
  }
  __shared__ float red[4];
  if (ln == 0) red[wv] = part;
  __syncthreads();
  if (tid == 0)
    unsafeAtomicAdd(out, -(red[0] + red[1] + red[2] + red[3]) * (1.0f / 32768.0f));
}

// ---------------------------------------------------------------------------
extern "C" void kernel_launch(void* const* d_in, const int* in_sizes, int n_in,
                              void* d_out, int out_size, void* d_ws, size_t ws_size,
                              hipStream_t stream) {
  (void)in_sizes; (void)n_in; (void)out_size; (void)ws_size;
  const float* z1 = (const float*)d_in[0];
  const float* z2 = (const float*)d_in[1];
  const float* w  = (const float*)d_in[2];
  float* out = (float*)d_out;
  char* ws = (char*)d_ws;
  // workspace layout
  unsigned short* zc    = (unsigned short*)ws;                         // 67,108,864 B
  float*          rnorm = (float*)(ws + (size_t)67108864);             //    262,144 B
  unsigned short* wnb   = (unsigned short*)(ws + (size_t)67371008);    //    524,288 B
  float*          T     = (float*)(ws + (size_t)67895296);             //     81,920 B

  hipLaunchKernelGGL(prep_kernel, dim3(16512), dim3(256), 0, stream, z1, z2, w, rnorm, wnb);
  hipLaunchKernelGGL(initvecs_kernel, dim3(80), dim3(256), 0, stream, T, out);
  hipLaunchKernelGGL(gemm_kernel, dim3(4, 512), dim3(256), 0, stream, z1, z2, rnorm, wnb, zc);
  hipLaunchKernelGGL(pass_kernel, dim3(512), dim3(256), 0, stream, zc, T, T, 0);
  for (int i = 1; i < 20; i++)
    hipLaunchKernelGGL(pass_kernel, dim3(512), dim3(256), 0, stream,
                       zc, T + (size_t)(i-1)*1024, T + (size_t)i*1024, 1);
  hipLaunchKernelGGL(loss_kernel, dim3(512), dim3(256), 0, stream, zc, T + 19*1024, out);
}

// Round 2
// 688.993 us; speedup vs baseline: 1.1681x; 1.1681x over previous
//
#include <hip/hip_runtime.h>
#include <stdint.h>

#define NROWS 32768
#define DDIM  512
#define KDIM  512

__device__ __forceinline__ float b2f(unsigned short u) {
  return __uint_as_float(((unsigned int)u) << 16);
}
__device__ __forceinline__ unsigned short f2bf(float f) {
  unsigned int u = __float_as_uint(f);
  u += 0x7FFFu + ((u >> 16) & 1u);   // round-to-nearest-even
  return (unsigned short)(u >> 16);
}

typedef __attribute__((ext_vector_type(8))) short bf16x8;
typedef __attribute__((ext_vector_type(4))) float f32x4;

// ---------------------------------------------------------------------------
// prep: row inverse-norms for z1/z2 (rows 0..65535) and normalized bf16 weight
// ---------------------------------------------------------------------------
__global__ __launch_bounds__(256) void prep_kernel(
    const float* __restrict__ z1, const float* __restrict__ z2,
    const float* __restrict__ w, float* __restrict__ rnorm,
    unsigned short* __restrict__ wnb) {
  const int tid = threadIdx.x;
  const int wv = tid >> 6, ln = tid & 63;
  const int row = blockIdx.x * 4 + wv;   // 0..66047
  const float* src;
  if (row < NROWS)        src = z1 + (size_t)row * DDIM;
  else if (row < 2*NROWS) src = z2 + (size_t)(row - NROWS) * DDIM;
  else                    src = w  + (size_t)(row - 2*NROWS) * DDIM;
  float4 v0 = ((const float4*)src)[ln*2];
  float4 v1 = ((const float4*)src)[ln*2+1];
  float ss = v0.x*v0.x + v0.y*v0.y + v0.z*v0.z + v0.w*v0.w
           + v1.x*v1.x + v1.y*v1.y + v1.z*v1.z + v1.w*v1.w;
  #pragma unroll
  for (int off = 1; off < 64; off <<= 1) ss += __shfl_xor(ss, off);
  float rn = 1.0f / fmaxf(sqrtf(ss), 1e-12f);
  if (row < 2*NROWS) {
    if (ln == 0) rnorm[row] = rn;
  } else {
    int r = row - 2*NROWS;
    ushort4 o0 = make_ushort4(f2bf(v0.x*rn), f2bf(v0.y*rn), f2bf(v0.z*rn), f2bf(v0.w*rn));
    ushort4 o1 = make_ushort4(f2bf(v1.x*rn), f2bf(v1.y*rn), f2bf(v1.z*rn), f2bf(v1.w*rn));
    ushort4* dst = (ushort4*)(wnb + (size_t)r*DDIM + ln*8);
    dst[0] = o0; dst[1] = o1;
  }
}

// ---------------------------------------------------------------------------
// initvecs: zero the 20 column-sum buffers (T[20][2*512]) and the output
// ---------------------------------------------------------------------------
__global__ void initvecs_kernel(float* __restrict__ T, float* __restrict__ out) {
  int i = blockIdx.x * 256 + threadIdx.x;
  if (i < 20 * 1024) T[i] = 0.f;
  if (i == 0) out[0] = 0.f;
}

// ---------------------------------------------------------------------------
// gemm: zc[r,c] = sum_d (z[r,d]*rnorm[r]) * wnb[c,d]   (bf16 MFMA, A*B^T)
// 128x128 tile, BK=32, 4 waves each 64x64 via 4x4 of 16x16x32 MFMAs
// ---------------------------------------------------------------------------
__global__ __launch_bounds__(256) void gemm_kernel(
    const float* __restrict__ z1, const float* __restrict__ z2,
    const float* __restrict__ rnorm, const unsigned short* __restrict__ wnb,
    unsigned short* __restrict__ zc) {
  constexpr int LDT = 40;   // padded LDS stride (elements): 80B rows, 16B aligned
  __shared__ unsigned short As[128 * LDT];
  __shared__ unsigned short Bs[128 * LDT];
  const int tid = threadIdx.x;
  const int colBase = blockIdx.x * 128;
  const int rowBase = blockIdx.y * 128;
  const float* Aptr = (rowBase < NROWS) ? (z1 + (size_t)rowBase * DDIM)
                                        : (z2 + (size_t)(rowBase - NROWS) * DDIM);
  const int wv = tid >> 6, ln = tid & 63;
  const int wm = wv & 1, wn = wv >> 1;
  const int lrow = ln & 15, quad = ln >> 4;

  f32x4 acc[4][4] = {};

  for (int k0 = 0; k0 < DDIM; k0 += 32) {
    // stage A (fp32 -> normalized bf16): 128 rows x 32 k
    #pragma unroll
    for (int i = 0; i < 4; i++) {
      int idx = i * 256 + tid;            // 0..1023
      int r = idx >> 3;                   // 0..127
      int kk = (idx & 7) * 4;             // 0..28
      float4 v = *(const float4*)(Aptr + (size_t)r * DDIM + k0 + kk);
      float rn = rnorm[rowBase + r];
      ushort4 o = make_ushort4(f2bf(v.x*rn), f2bf(v.y*rn), f2bf(v.z*rn), f2bf(v.w*rn));
      *(ushort4*)(&As[r * LDT + kk]) = o;
    }
    // stage B (bf16 weight): 128 rows x 32 k
    #pragma unroll
    for (int i = 0; i < 2; i++) {
      int idx = i * 256 + tid;            // 0..511
      int r = idx >> 2;                   // 0..127
      int kk = (idx & 3) * 8;             // 0..24
      float4 v = *(const float4*)(wnb + (size_t)(colBase + r) * DDIM + k0 + kk);
      *(float4*)(&Bs[r * LDT + kk]) = v;
    }
    __syncthreads();
    bf16x8 af[4], bfr[4];
    #pragma unroll
    for (int mi = 0; mi < 4; mi++)
      af[mi] = *(const bf16x8*)(&As[(64*wm + 16*mi + lrow) * LDT + quad*8]);
    #pragma unroll
    for (int ni = 0; ni < 4; ni++)
      bfr[ni] = *(const bf16x8*)(&Bs[(64*wn + 16*ni + lrow) * LDT + quad*8]);
    #pragma unroll
    for (int mi = 0; mi < 4; mi++)
      #pragma unroll
      for (int ni = 0; ni < 4; ni++)
        acc[mi][ni] = __builtin_amdgcn_mfma_f32_16x16x32_bf16(
            af[mi], bfr[ni], acc[mi][ni], 0, 0, 0);
    __syncthreads();
  }
  // epilogue: C/D layout col=lane&15, row=(lane>>4)*4+reg
  #pragma unroll
  for (int mi = 0; mi < 4; mi++)
    #pragma unroll
    for (int ni = 0; ni < 4; ni++)
      #pragma unroll
      for (int r = 0; r < 4; r++) {
        size_t grow = (size_t)rowBase + 64*wm + 16*mi + quad*4 + r;
        int gcol = colBase + 64*wn + 16*ni + lrow;
        zc[grow * KDIM + gcol] = f2bf(acc[mi][ni][r]);
      }
}

// ---------------------------------------------------------------------------
// sinkhorn fused pass over both matrices (16 waves/block, 8 rows/wave):
//   mode 0: T0[k] = sum_rows exp(zc/eps)              (b == 1)
//   mode 1: a_k = 1/(K*Tprev[k]); per row s = sum_k M*a; b = 1/(B*s);
//           Tnext[k] += sum_rows M[k]*b
// blocks 0..255 -> matrix 0 (zc1), 256..511 -> matrix 1 (zc2)
// ---------------------------------------------------------------------------
__global__ __launch_bounds__(1024) void pass_kernel(
    const unsigned short* __restrict__ zc,
    const float* __restrict__ Tprev, float* __restrict__ Tnext, int mode) {
  __shared__ float red[16 * 512];
  const int tid = threadIdx.x;
  const int wv = tid >> 6, ln = tid & 63;
  const int gw = blockIdx.x * 16 + wv;      // 0..8191
  const size_t row0 = (size_t)gw * 8;
  const int mat = blockIdx.x >> 8;          // 0 or 1 (block-uniform)
  float a[8];
  if (mode) {
    #pragma unroll
    for (int j = 0; j < 8; j++) a[j] = 1.0f / (512.0f * Tprev[mat*512 + ln*8 + j]);
  }
  float acc[8] = {0,0,0,0,0,0,0,0};
  const unsigned short* base = zc + row0 * 512 + ln * 8;
  #pragma unroll
  for (int r = 0; r < 8; r++) {
    const ushort4* p = (const ushort4*)(base + (size_t)r * 512);
    ushort4 u0 = p[0], u1 = p[1];
    float e[8];
    e[0]=__expf(b2f(u0.x)*20.f); e[1]=__expf(b2f(u0.y)*20.f);
    e[2]=__expf(b2f(u0.z)*20.f); e[3]=__expf(b2f(u0.w)*20.f);
    e[4]=__expf(b2f(u1.x)*20.f); e[5]=__expf(b2f(u1.y)*20.f);
    e[6]=__expf(b2f(u1.z)*20.f); e[7]=__expf(b2f(u1.w)*20.f);
    if (mode) {
      float part = e[0]*a[0]+e[1]*a[1]+e[2]*a[2]+e[3]*a[3]
                 + e[4]*a[4]+e[5]*a[5]+e[6]*a[6]+e[7]*a[7];
      #pragma unroll
      for (int off = 1; off < 64; off <<= 1) part += __shfl_xor(part, off);
      float b = 1.0f / (32768.0f * part);
      #pragma unroll
      for (int j = 0; j < 8; j++) acc[j] += e[j] * b;
    } else {
      #pragma unroll
      for (int j = 0; j < 8; j++) acc[j] += e[j];
    }
  }
  #pragma unroll
  for (int j = 0; j < 8; j++) red[wv*512 + ln*8 + j] = acc[j];
  __syncthreads();
  if (tid < 512) {
    float s = 0.f;
    #pragma unroll
    for (int w = 0; w < 16; w++) s += red[w*512 + tid];
    unsafeAtomicAdd(&Tnext[mat*512 + tid], s);
  }
}

// ---------------------------------------------------------------------------
// loss: a20 = 1/(K*T19); per row: q = M*a/s (s = sum_k M*a);
// logp = z/tau - logsumexp(z/tau);  out -= (sum_k q1*logp2 + q2*logp1)/N
// 16 waves/block, 4 rows/wave, 512 blocks
// ---------------------------------------------------------------------------
__global__ __launch_bounds__(1024) void loss_kernel(
    const unsigned short* __restrict__ zc,
    const float* __restrict__ T19, float* __restrict__ out) {
  const int tid = threadIdx.x;
  const int wv = tid >> 6, ln = tid & 63;
  const int gw = blockIdx.x * 16 + wv;      // 0..8191
  const size_t row0 = (size_t)gw * 4;
  float a1[8], a2[8];
  #pragma unroll
  for (int j = 0; j < 8; j++) {
    a1[j] = 1.0f / (512.0f * T19[ln*8 + j]);
    a2[j] = 1.0f / (512.0f * T19[512 + ln*8 + j]);
  }
  const float invTau = 1.0f / 0.3f;
  float part = 0.f;
  for (int r = 0; r < 4; r++) {
    size_t b = row0 + r;
    const ushort4* p1 = (const ushort4*)(zc + b * 512 + ln * 8);
    const ushort4* p2 = (const ushort4*)(zc + (b + NROWS) * 512 + ln * 8);
    ushort4 u10 = p1[0], u11 = p1[1], u20 = p2[0], u21 = p2[1];
    float zf1[8], zf2[8];
    zf1[0]=b2f(u10.x); zf1[1]=b2f(u10.y); zf1[2]=b2f(u10.z); zf1[3]=b2f(u10.w);
    zf1[4]=b2f(u11.x); zf1[5]=b2f(u11.y); zf1[6]=b2f(u11.z); zf1[7]=b2f(u11.w);
    zf2[0]=b2f(u20.x); zf2[1]=b2f(u20.y); zf2[2]=b2f(u20.z); zf2[3]=b2f(u20.w);
    zf2[4]=b2f(u21.x); zf2[5]=b2f(u21.y); zf2[6]=b2f(u21.z); zf2[7]=b2f(u21.w);
    float m1 = -1e30f, m2 = -1e30f;
    #pragma unroll
    for (int j = 0; j < 8; j++) { m1 = fmaxf(m1, zf1[j]); m2 = fmaxf(m2, zf2[j]); }
    #pragma unroll
    for (int off = 1; off < 64; off <<= 1) {
      m1 = fmaxf(m1, __shfl_xor(m1, off));
      m2 = fmaxf(m2, __shfl_xor(m2, off));
    }
    float se1 = 0.f, se2 = 0.f;
    #pragma unroll
    for (int j = 0; j < 8; j++) {
      se1 += __expf((zf1[j] - m1) * invTau);
      se2 += __expf((zf2[j] - m2) * invTau);
    }
    #pragma unroll
    for (int off = 1; off < 64; off <<= 1) {
      se1 += __shfl_xor(se1, off);
      se2 += __shfl_xor(se2, off);
    }
    float ls1 = m1 * invTau + __logf(se1);
    float ls2 = m2 * invTau + __logf(se2);
    float s1 = 0.f, n1 = 0.f, s2 = 0.f, n2 = 0.f;
    #pragma unroll
    for (int j = 0; j < 8; j++) {
      float e1 = __expf(zf1[j] * 20.f) * a1[j];
      s1 += e1; n1 += e1 * (zf2[j] * invTau - ls2);
      float e2 = __expf(zf2[j] * 20.f) * a2[j];
      s2 += e2; n2 += e2 * (zf1[j] * invTau - ls1);
    }
    #pragma unroll
    for (int off = 1; off < 64; off <<= 1) {
      s1 += __shfl_xor(s1, off); n1 += __shfl_xor(n1, off);
      s2 += __shfl_xor(s2, off); n2 += __shfl_xor(n2, off);
    }
    part += n1 / s1 + n2 / s2;
  }
  __shared__ float red[16];
  if (ln == 0) red[wv] = part;
  __syncthreads();
  if (tid == 0) {
    float s = 0.f;
    #pragma unroll
    for (int w = 0; w < 16; w++) s += red[w];
    unsafeAtomicAdd(out, -s * (1.0f / 32768.0f));
  }
}

// ---------------------------------------------------------------------------
extern "C" void kernel_launch(void* const* d_in, const int* in_sizes, int n_in,
                              void* d_out, int out_size, void* d_ws, size_t ws_size,
                              hipStream_t stream) {
  (void)in_sizes; (void)n_in; (void)out_size; (void)ws_size;
  const float* z1 = (const float*)d_in[0];
  const float* z2 = (const float*)d_in[1];
  const float* w  = (const float*)d_in[2];
  float* out = (float*)d_out;
  char* ws = (char*)d_ws;
  // workspace layout
  unsigned short* zc    = (unsigned short*)ws;                         // 67,108,864 B
  float*          rnorm = (float*)(ws + (size_t)67108864);             //    262,144 B
  unsigned short* wnb   = (unsigned short*)(ws + (size_t)67371008);    //    524,288 B
  float*          T     = (float*)(ws + (size_t)67895296);             //     81,920 B

  hipLaunchKernelGGL(prep_kernel, dim3(16512), dim3(256), 0, stream, z1, z2, w, rnorm, wnb);
  hipLaunchKernelGGL(initvecs_kernel, dim3(80), dim3(256), 0, stream, T, out);
  hipLaunchKernelGGL(gemm_kernel, dim3(4, 512), dim3(256), 0, stream, z1, z2, rnorm, wnb, zc);
  hipLaunchKernelGGL(pass_kernel, dim3(512), dim3(1024), 0, stream, zc, T, T, 0);
  for (int i = 1; i < 20; i++)
    hipLaunchKernelGGL(pass_kernel, dim3(512), dim3(1024), 0, stream,
                       zc, T + (size_t)(i-1)*1024, T + (size_t)i*1024, 1);
  hipLaunchKernelGGL(loss_kernel, dim3(512), dim3(1024), 0, stream, zc, T + 19*1024, out);
}